// Round 4
// baseline (104.459 us; speedup 1.0000x reference)
//
#include <hip/hip_runtime.h>

#define NN 32
#define CC 256
#define KK 8192
#define PARTS 16
#define TPB 256
#define PADK 9216  // >= 8192 + 16*63 (buckets padded to multiples of 64)
#define MAX_INIT (-100.0f)

typedef unsigned int uint32;
typedef unsigned short ushort16;

// ---------------------------------------------------------------------------
// ws layout (bytes):
//   0      : counts   float[(NN+1)*PARTS]   rows 0..31 = pooled_count[n][p], row 32 = patch_count[p]
//   4096   : poff     uint[PARTS+1]         padded bucket offsets (multiples of 64)
//   8192   : permbase ushort[PADK]          k | (isPad<<15); pads carry first-real k of their part
//   28672  : partOf   uchar[PADK]
//   40960  : vmperm   ushort[NN*PADK]       k | (valid<<15)  (valid=0 for pads)
// ---------------------------------------------------------------------------

// Single-block stable counting sort of labels into padded part buckets.
__global__ __launch_bounds__(TPB) void sort_kernel(const int* __restrict__ labels,
                                                   float* __restrict__ counts,
                                                   uint32* __restrict__ poff_g,
                                                   ushort16* __restrict__ permbase,
                                                   unsigned char* __restrict__ partOf) {
    __shared__ ushort16 lh[PARTS][TPB];    // per-thread histograms (max 32 each)
    __shared__ uint32 pexc[PARTS][TPB];    // exclusive prefix over threads, per part
    __shared__ uint32 wtot[PARTS][4];
    __shared__ uint32 s_off[PARTS + 1];
    __shared__ uint32 s_hist[PARTS];
    __shared__ ushort16 s_perm[PADK];
    const int t = threadIdx.x;
    const int CH = KK / TPB;  // 32
    const int w = t >> 6;

#pragma unroll
    for (int p = 0; p < PARTS; ++p) lh[p][t] = 0;
    __syncthreads();
    for (int i = 0; i < CH; ++i) {
        int p = labels[t * CH + i] & 15;
        lh[p][t]++;
    }
    __syncthreads();
    // parallel exclusive scan over the 256 thread-histograms, per part
    for (int p = 0; p < PARTS; ++p) {
        uint32 v = lh[p][t];
        uint32 inc = v;
#pragma unroll
        for (int s = 1; s < 64; s <<= 1) {
            uint32 o = __shfl_up(inc, s, 64);
            if ((t & 63) >= s) inc += o;
        }
        pexc[p][t] = inc - v;  // exclusive within wave
        if ((t & 63) == 63) wtot[p][w] = inc;
    }
    __syncthreads();
    for (int p = 0; p < PARTS; ++p) {
        uint32 base = 0;
        for (int ww = 0; ww < w; ++ww) base += wtot[p][ww];
        pexc[p][t] += base;
    }
    __syncthreads();
    if (t < PARTS) s_hist[t] = pexc[t][TPB - 1] + lh[t][TPB - 1];
    __syncthreads();
    if (t == 0) {
        uint32 off = 0;
        for (int p = 0; p < PARTS; ++p) {
            s_off[p] = off;
            off += (s_hist[p] + 63u) & ~63u;
            counts[NN * PARTS + p] = (float)s_hist[p];  // patch_count
        }
        s_off[PARTS] = off;
    }
    __syncthreads();
    // stable scatter (reuse lh as running per-thread counter)
#pragma unroll
    for (int p = 0; p < PARTS; ++p) lh[p][t] = 0;
    for (int i = 0; i < CH; ++i) {
        int k = t * CH + i;
        int p = labels[k] & 15;
        uint32 pos = s_off[p] + pexc[p][t] + lh[p][t];
        lh[p][t]++;
        s_perm[pos] = (ushort16)k;
    }
    __syncthreads();
    const uint32 end = s_off[PARTS];
    for (uint32 jp = t; jp < PADK; jp += TPB) {
        if (jp >= end) {
            permbase[jp] = 0;
            partOf[jp] = 0;
            continue;
        }
        int p = 0;
#pragma unroll
        for (int q = 1; q < PARTS; ++q) p += (jp >= s_off[q]) ? 1 : 0;
        ushort16 v;
        if (jp < s_off[p] + s_hist[p])
            v = s_perm[jp];  // real element
        else
            v = (ushort16)((s_hist[p] ? s_perm[s_off[p]] : 0) | 0x8000u);  // pad -> first real k
        permbase[jp] = v;
        partOf[jp] = (unsigned char)p;
    }
    if (t <= PARTS) poff_g[t] = s_off[t];
}

// Per-n: bake vm into the permuted side data and compute pooled_count[n][p].
__global__ __launch_bounds__(TPB) void side_kernel(const int* __restrict__ vm,
                                                   const uint32* __restrict__ poff_g,
                                                   const ushort16* __restrict__ permbase,
                                                   const unsigned char* __restrict__ partOf,
                                                   float* __restrict__ counts,
                                                   ushort16* __restrict__ vmperm) {
    __shared__ float cnt[PARTS * TPB];
    const int t = threadIdx.x;
    const int n = blockIdx.x;
#pragma unroll
    for (int p = 0; p < PARTS; ++p) cnt[p * TPB + t] = 0.0f;
    __syncthreads();
    const uint32 end = poff_g[PARTS];
    const int* __restrict__ vmn = vm + (size_t)n * KK;
    ushort16* __restrict__ vpn = vmperm + (size_t)n * PADK;
    for (uint32 jp = t; jp < end; jp += TPB) {
        uint32 u = permbase[jp];
        int p = partOf[jp];
        uint32 k = u & 0x1fffu;
        int valid = (u & 0x8000u) ? 0 : (vmn[k] ? 1 : 0);
        vpn[jp] = (ushort16)(k | (valid << 15));
        cnt[p * TPB + t] += (float)valid;
    }
    __syncthreads();
    for (int s = TPB / 2; s > 0; s >>= 1) {
        if (t < s) {
#pragma unroll
            for (int p = 0; p < PARTS; ++p) cnt[p * TPB + t] += cnt[p * TPB + t + s];
        }
        __syncthreads();
    }
    if (t < PARTS) counts[n * PARTS + t] = cnt[t * TPB];
}

// One block per (n,c) row. Stage the row into LDS via global_load_lds
// (linear dest, uniform base + lane*16 — the m97 pattern), then gather in
// sorted order with STRIDE-1 lane interleave (adjacent lanes -> adjacent
// sorted ranks -> k-gaps ~Geom(16) -> banks well mixed). Accumulate in
// registers, 4-way unrolled for ILP.
__global__ __launch_bounds__(TPB) void pool_kernel(const float* __restrict__ feats,
                                                   const ushort16* __restrict__ vmperm,
                                                   const uint32* __restrict__ poff_g,
                                                   const float* __restrict__ counts,
                                                   float* __restrict__ out) {
    __shared__ float row[KK];  // 32 KB -> 5 blocks/CU
    const int t = threadIdx.x;
    const int b = blockIdx.x;  // n*256 + c
    const int n = b >> 8;
    const int g = t >> 4;      // part owned by this 16-thread group
    const int l = t & 15;
    const int w = t >> 6;      // wave id (0..3)
    const int lane = t & 63;

    const float* __restrict__ frow = feats + (size_t)b * KK;
    // Each wave stages 8 contiguous 1 KiB segments: lane i's 16B goes to
    // ldsbase + i*16 (hardware-defined), matching the linear layout.
#pragma unroll
    for (int i = 0; i < 8; ++i) {
        const int seg = w * 8 + i;  // 32 segments of 256 floats
        __builtin_amdgcn_global_load_lds(
            (const __attribute__((address_space(1))) unsigned int*)(frow + seg * 256 + lane * 4),
            (__attribute__((address_space(3))) unsigned int*)&row[seg * 256],
            16, 0, 0);
    }

    const uint32 jbeg = poff_g[g];
    const uint32 jend = poff_g[g + 1];
    const ushort16* __restrict__ vpn = vmperm + (size_t)n * PADK;
    __syncthreads();  // drains vmcnt(0) before barrier

    float rs0 = 0.0f, rs1 = 0.0f, rs2 = 0.0f, rs3 = 0.0f;
    float rm0 = MAX_INIT, rm1 = MAX_INIT, rm2 = MAX_INIT, rm3 = MAX_INIT;
    // bucket sizes are multiples of 64 -> exact trip count, no tail
    for (uint32 jp = jbeg + l; jp < jend; jp += 64) {
        uint32 u0 = vpn[jp];
        uint32 u1 = vpn[jp + 16];
        uint32 u2 = vpn[jp + 32];
        uint32 u3 = vpn[jp + 48];
        float f0 = row[u0 & 0x1fffu];
        float f1 = row[u1 & 0x1fffu];
        float f2 = row[u2 & 0x1fffu];
        float f3 = row[u3 & 0x1fffu];
        rm0 = fmaxf(rm0, f0);
        rs0 += (u0 & 0x8000u) ? f0 : 0.0f;
        rm1 = fmaxf(rm1, f1);
        rs1 += (u1 & 0x8000u) ? f1 : 0.0f;
        rm2 = fmaxf(rm2, f2);
        rs2 += (u2 & 0x8000u) ? f2 : 0.0f;
        rm3 = fmaxf(rm3, f3);
        rs3 += (u3 & 0x8000u) ? f3 : 0.0f;
    }

    float rs = (rs0 + rs1) + (rs2 + rs3);
    float rm = fmaxf(fmaxf(rm0, rm1), fmaxf(rm2, rm3));
#pragma unroll
    for (int m = 8; m >= 1; m >>= 1) {
        rs += __shfl_xor(rs, m, 64);
        rm = fmaxf(rm, __shfl_xor(rm, m, 64));
    }
    if (l == 0) {
        float cv = counts[n * PARTS + g];
        float pc = counts[NN * PARTS + g];
        out[(size_t)b * PARTS + g] = rs / fmaxf(cv, 1.0f) + (pc > 0.0f ? rm : 0.0f);
    }
}

extern "C" void kernel_launch(void* const* d_in, const int* in_sizes, int n_in,
                              void* d_out, int out_size, void* d_ws, size_t ws_size,
                              hipStream_t stream) {
    const float* feats  = (const float*)d_in[0];
    const int*   labels = (const int*)d_in[1];
    const int*   vm     = (const int*)d_in[2];
    float* out = (float*)d_out;

    float*         counts   = (float*)d_ws;
    uint32*        poff     = (uint32*)((char*)d_ws + 4096);
    ushort16*      permbase = (ushort16*)((char*)d_ws + 8192);
    unsigned char* partOf   = (unsigned char*)((char*)d_ws + 28672);
    ushort16*      vmperm   = (ushort16*)((char*)d_ws + 40960);

    sort_kernel<<<1, TPB, 0, stream>>>(labels, counts, poff, permbase, partOf);
    side_kernel<<<NN, TPB, 0, stream>>>(vm, poff, permbase, partOf, counts, vmperm);
    pool_kernel<<<NN * CC, TPB, 0, stream>>>(feats, vmperm, poff, counts, out);
}

// Round 5
// 86.390 us; speedup vs baseline: 1.2092x; 1.2092x over previous
//
#include <hip/hip_runtime.h>

#define NN 32
#define CC 256
#define KK 8192
#define PARTS 16
#define TPB 256
#define CH 8                 // c-rows per block
#define NCHUNK (CC / CH)     // 32 chunks -> grid = 32*32 = 1024 blocks
#define PADB 9216            // perm entries; buckets padded to x64
#define MAX_INIT (-100.0f)

typedef unsigned int uint32;
typedef unsigned short u16;

// Single fused kernel. Each block:
//  Phase 1: block-local counting sort of labels (vm[n] baked in) -> LDS perm
//           + per-part valid counts + patch histogram. No global scratch.
//  Phase 2: for CH c-rows: stage row via global_load_lds, gather in sorted
//           order (registers accumulate), 16-lane shfl reduce, write out.
// Sort transients (lh/cnt/pexc, 24 KB) alias the row buffer (dead after sort).
__global__ __launch_bounds__(TPB) void fused_kernel(const float* __restrict__ feats,
                                                    const int* __restrict__ labels,
                                                    const int* __restrict__ vm,
                                                    float* __restrict__ out) {
    __shared__ float row[KK];            // 32 KB (aliased during sort)
    __shared__ u16 perm[PADB];           // 18 KB, persists: k | valid<<15
    __shared__ uint32 s_off[PARTS + 1];  // padded bucket offsets (x64)
    __shared__ u16 s_hist[PARTS];        // patch_count per part
    __shared__ u16 wtot[PARTS][4];

    u16* lh   = (u16*)row;                    // [16][256] hist / scatter counters
    u16* cnt  = (u16*)row + PARTS * TPB;      // [16][256] valid counts
    u16* pexc = (u16*)row + 2 * PARTS * TPB;  // [16][256] exclusive prefix

    const int t = threadIdx.x;
    const int blk = blockIdx.x;
    const int n  = blk / NCHUNK;
    const int c0 = (blk % NCHUNK) * CH;
    const int w = t >> 6;
    const int lane = t & 63;
    const int g = t >> 4;                // part owned by this 16-thread group
    const int l = t & 15;

    // ---------------- Phase 1: local counting sort ----------------
#pragma unroll
    for (int p = 0; p < PARTS; ++p) { lh[p * TPB + t] = 0; cnt[p * TPB + t] = 0; }

    int4 lv[8], vv[8];
    {
        const int4* l4 = (const int4*)labels + t * 8;            // k = t*32 .. t*32+31
        const int4* v4 = (const int4*)(vm + (size_t)n * KK) + t * 8;
#pragma unroll
        for (int i = 0; i < 8; ++i) { lv[i] = l4[i]; vv[i] = v4[i]; }
    }
    __syncthreads();

    // per-thread histogram (own column -> no cross-thread hazard)
#pragma unroll
    for (int i = 0; i < 8; ++i) {
        int la[4] = {lv[i].x, lv[i].y, lv[i].z, lv[i].w};
#pragma unroll
        for (int j = 0; j < 4; ++j) lh[(la[j] & 15) * TPB + t]++;
    }
    __syncthreads();

    // per-part exclusive scan over the 256 thread-histograms
    for (int p = 0; p < PARTS; ++p) {
        uint32 v = lh[p * TPB + t];
        uint32 inc = v;
#pragma unroll
        for (int s = 1; s < 64; s <<= 1) {
            uint32 o = __shfl_up(inc, s, 64);
            if (lane >= s) inc += o;
        }
        pexc[p * TPB + t] = (u16)(inc - v);
        if (lane == 63) wtot[p][w] = (u16)inc;
    }
    __syncthreads();
    for (int p = 0; p < PARTS; ++p) {
        uint32 base = 0;
        for (int ww = 0; ww < w; ++ww) base += wtot[p][ww];
        pexc[p * TPB + t] = (u16)(pexc[p * TPB + t] + base);
    }
    __syncthreads();
    if (t < PARTS) s_hist[t] = (u16)(pexc[t * TPB + TPB - 1] + lh[t * TPB + TPB - 1]);
    __syncthreads();
    if (t == 0) {
        uint32 off = 0;
#pragma unroll
        for (int p = 0; p < PARTS; ++p) {
            s_off[p] = off;
            off += ((uint32)s_hist[p] + 63u) & ~63u;
        }
        s_off[PARTS] = off;
    }
    __syncthreads();

    // stable scatter with vm baked in (reset lh as running counters)
#pragma unroll
    for (int p = 0; p < PARTS; ++p) lh[p * TPB + t] = 0;
    // own-column reset; s_off visible (barrier above). No barrier needed here.
#pragma unroll
    for (int i = 0; i < 8; ++i) {
        int la[4] = {lv[i].x, lv[i].y, lv[i].z, lv[i].w};
        int va[4] = {vv[i].x, vv[i].y, vv[i].z, vv[i].w};
#pragma unroll
        for (int j = 0; j < 4; ++j) {
            int k = t * 32 + i * 4 + j;
            int p = la[j] & 15;
            u16 c = lh[p * TPB + t];
            uint32 pos = s_off[p] + (uint32)pexc[p * TPB + t] + c;
            lh[p * TPB + t] = (u16)(c + 1);
            perm[pos] = (u16)(k | (va[j] ? 0x8000 : 0));
            if (va[j]) cnt[p * TPB + t]++;
        }
    }
    __syncthreads();

    // pad fill: pads replay the bucket's first real element with valid=0
    if (t < PARTS) {
        uint32 beg = s_off[t] + s_hist[t];
        uint32 end = s_off[t + 1];
        u16 fill = s_hist[t] ? (u16)(perm[s_off[t]] & 0x1fffu) : (u16)0;
        for (uint32 jp = beg; jp < end; ++jp) perm[jp] = fill;
    }
    __syncthreads();

    // reduce valid counts over threads
    for (int s = 128; s > 0; s >>= 1) {
        if (t < s) {
#pragma unroll
            for (int p = 0; p < PARTS; ++p)
                cnt[p * TPB + t] = (u16)(cnt[p * TPB + t] + cnt[p * TPB + t + s]);
        }
        __syncthreads();
    }

    // snapshot per-group scalars to registers before row buffer is reused
    const float cv = fmaxf((float)cnt[g * TPB], 1.0f);
    const int ph = s_hist[g];
    const uint32 jbeg = s_off[g];
    const uint32 jend = s_off[g + 1];
    __syncthreads();

    // ---------------- Phase 2: stream CH rows ----------------
    for (int r = 0; r < CH; ++r) {
        const float* __restrict__ frow = feats + ((size_t)(n * CC + c0 + r)) * KK;
#pragma unroll
        for (int i = 0; i < 8; ++i) {
            const int seg = w * 8 + i;  // 32 segments of 256 floats
            __builtin_amdgcn_global_load_lds(
                (const __attribute__((address_space(1))) unsigned int*)(frow + seg * 256 + lane * 4),
                (__attribute__((address_space(3))) unsigned int*)&row[seg * 256],
                16, 0, 0);
        }
        __syncthreads();  // drains vmcnt before barrier

        float rs0 = 0.0f, rs1 = 0.0f, rs2 = 0.0f, rs3 = 0.0f;
        float rm0 = MAX_INIT, rm1 = MAX_INIT, rm2 = MAX_INIT, rm3 = MAX_INIT;
        for (uint32 jp = jbeg + l; jp < jend; jp += 64) {
            uint32 u0 = perm[jp];
            uint32 u1 = perm[jp + 16];
            uint32 u2 = perm[jp + 32];
            uint32 u3 = perm[jp + 48];
            float f0 = row[u0 & 0x1fffu];
            float f1 = row[u1 & 0x1fffu];
            float f2 = row[u2 & 0x1fffu];
            float f3 = row[u3 & 0x1fffu];
            rm0 = fmaxf(rm0, f0);
            rs0 += (u0 & 0x8000u) ? f0 : 0.0f;
            rm1 = fmaxf(rm1, f1);
            rs1 += (u1 & 0x8000u) ? f1 : 0.0f;
            rm2 = fmaxf(rm2, f2);
            rs2 += (u2 & 0x8000u) ? f2 : 0.0f;
            rm3 = fmaxf(rm3, f3);
            rs3 += (u3 & 0x8000u) ? f3 : 0.0f;
        }

        float rs = (rs0 + rs1) + (rs2 + rs3);
        float rm = fmaxf(fmaxf(rm0, rm1), fmaxf(rm2, rm3));
#pragma unroll
        for (int m = 8; m >= 1; m >>= 1) {
            rs += __shfl_xor(rs, m, 64);
            rm = fmaxf(rm, __shfl_xor(rm, m, 64));
        }
        if (l == 0) {
            out[((size_t)(n * CC + c0 + r)) * PARTS + g] = rs / cv + (ph ? rm : 0.0f);
        }
        __syncthreads();  // protect row before next stage
    }
}

extern "C" void kernel_launch(void* const* d_in, const int* in_sizes, int n_in,
                              void* d_out, int out_size, void* d_ws, size_t ws_size,
                              hipStream_t stream) {
    const float* feats  = (const float*)d_in[0];
    const int*   labels = (const int*)d_in[1];
    const int*   vm     = (const int*)d_in[2];
    float* out = (float*)d_out;

    fused_kernel<<<NN * NCHUNK, TPB, 0, stream>>>(feats, labels, vm, out);
}

// Round 6
// 67.226 us; speedup vs baseline: 1.5539x; 1.2851x over previous
//
#include <hip/hip_runtime.h>

#define NN 32
#define CC 256
#define KK 8192
#define PARTS 16
#define TPB 256
#define PSTR 768            // perm entries per part (fixed stride); 48 per lane
#define CH 16               // rows per block -> grid 512 = exactly 2 blocks/CU
#define NCH (CC / CH)       // 16
#define MAX_INIT (-100.0f)

typedef unsigned int uint32;
typedef unsigned short u16;

// ---------------------------------------------------------------------------
// ws layout: pcount int[16] at byte 0; permbase u16[16*768] at byte 64.
// perm entry: k (13 bits) | pad-flag 0x4000. Pads replicate the bucket's
// first real k (max-neutral); valid bit is NOT stored here (folded per-n
// in the pool kernel from a vm bitmask).
// ---------------------------------------------------------------------------

// One-block counting sort of the shared label array (proven R5 structure).
__global__ __launch_bounds__(TPB) void sortA(const int* __restrict__ labels,
                                             int* __restrict__ pcount,
                                             u16* __restrict__ permbase) {
    __shared__ u16 lh[PARTS * TPB];
    __shared__ u16 pexc[PARTS * TPB];
    __shared__ u16 wtot[PARTS][4];
    __shared__ u16 s_hist[PARTS];
    __shared__ __align__(16) u16 s_perm[PARTS * PSTR];  // 24 KB
    const int t = threadIdx.x;
    const int w = t >> 6;
    const int lane = t & 63;

#pragma unroll
    for (int p = 0; p < PARTS; ++p) lh[p * TPB + t] = 0;
    int4 lv[8];
    const int4* l4 = (const int4*)labels + t * 8;  // k = t*32 + i*4 + j
#pragma unroll
    for (int i = 0; i < 8; ++i) lv[i] = l4[i];
    __syncthreads();

#pragma unroll
    for (int i = 0; i < 8; ++i) {
        int la[4] = {lv[i].x, lv[i].y, lv[i].z, lv[i].w};
#pragma unroll
        for (int j = 0; j < 4; ++j) lh[(la[j] & 15) * TPB + t]++;
    }
    __syncthreads();

    for (int p = 0; p < PARTS; ++p) {
        uint32 v = lh[p * TPB + t];
        uint32 inc = v;
#pragma unroll
        for (int s = 1; s < 64; s <<= 1) {
            uint32 o = __shfl_up(inc, s, 64);
            if (lane >= s) inc += o;
        }
        pexc[p * TPB + t] = (u16)(inc - v);
        if (lane == 63) wtot[p][w] = (u16)inc;
    }
    __syncthreads();
    for (int p = 0; p < PARTS; ++p) {
        uint32 base = 0;
        for (int ww = 0; ww < w; ++ww) base += wtot[p][ww];
        pexc[p * TPB + t] = (u16)(pexc[p * TPB + t] + base);
    }
    __syncthreads();
    if (t < PARTS) s_hist[t] = (u16)(pexc[t * TPB + TPB - 1] + lh[t * TPB + TPB - 1]);
    __syncthreads();

    // stable scatter (own-column counters)
#pragma unroll
    for (int p = 0; p < PARTS; ++p) lh[p * TPB + t] = 0;
#pragma unroll
    for (int i = 0; i < 8; ++i) {
        int la[4] = {lv[i].x, lv[i].y, lv[i].z, lv[i].w};
#pragma unroll
        for (int j = 0; j < 4; ++j) {
            int k = t * 32 + i * 4 + j;
            int p = la[j] & 15;
            u16 c = lh[p * TPB + t];
            uint32 q = (uint32)pexc[p * TPB + t] + c;
            lh[p * TPB + t] = (u16)(c + 1);
            if (q < PSTR) s_perm[p * PSTR + q] = (u16)k;  // guard: impossible overflow
        }
    }
    __syncthreads();

    // pad fill + patch counts
    if (t < PARTS) {
        int p = t;
        uint32 beg = s_hist[p];
        u16 fill = (u16)((beg ? (s_perm[p * PSTR] & 0x1fffu) : 0u) | 0x4000u);
        for (uint32 q = beg; q < PSTR; ++q) s_perm[p * PSTR + q] = fill;
        pcount[p] = (int)s_hist[p];
    }
    __syncthreads();

    const uint4* src = (const uint4*)s_perm;
    uint4* dst = (uint4*)permbase;  // 1536 uint4
#pragma unroll
    for (int j = 0; j < 6; ++j) dst[j * TPB + t] = src[j * TPB + t];
}

// Pool: grid 512 (n x 16-row chunk). Perm in registers (48 entries/lane),
// validity folded once per block into a 48-bit register mask. Rows stream
// through a double-buffered 64 KB LDS via global_load_lds with COUNTED
// vmcnt (raw s_barrier, never drain to 0 mid-loop) -> next row's loads
// stay in flight while gathering the current row.
__global__ __launch_bounds__(TPB) void pool_kernel(const float* __restrict__ feats,
                                                   const u16* __restrict__ permbase,
                                                   const int* __restrict__ pcount,
                                                   const int* __restrict__ vm,
                                                   float* __restrict__ out) {
    __shared__ uint32 srow[2 * KK];  // 64 KB; first 256 words alias the vm bitmask
    const int t = threadIdx.x;
    const int blk = blockIdx.x;
    const int n = blk / NCH;
    const int c0 = (blk % NCH) * CH;
    const int w = t >> 6;
    const int lane = t & 63;
    const int g = t >> 4;  // part owned by this 16-thread group
    const int l = t & 15;

    // ---- prologue: vm bitmask (aliased in srow[0..255]) ----
    {
        const int4* vmn4 = (const int4*)(vm + (size_t)n * KK) + t * 8;
        uint32 bits = 0;
#pragma unroll
        for (int j = 0; j < 8; ++j) {
            int4 v = vmn4[j];
            bits |= (uint32)(v.x != 0) << (4 * j) | (uint32)(v.y != 0) << (4 * j + 1) |
                    (uint32)(v.z != 0) << (4 * j + 2) | (uint32)(v.w != 0) << (4 * j + 3);
        }
        srow[t] = bits;
    }

    // ---- perm entries -> 24 registers/lane (compile-time indexed) ----
    uint32 pk[24];
    {
        const uint4* pb4 = (const uint4*)(permbase + g * PSTR + l * 48);  // 96 B/lane
#pragma unroll
        for (int j = 0; j < 6; ++j) {
            uint4 q = pb4[j];
            pk[j * 4 + 0] = q.x;
            pk[j * 4 + 1] = q.y;
            pk[j * 4 + 2] = q.z;
            pk[j * 4 + 3] = q.w;
        }
    }
    __syncthreads();  // bitmask visible

    uint32 vb0 = 0, vb1 = 0;
#pragma unroll
    for (int i = 0; i < 48; ++i) {
        uint32 e = (pk[i >> 1] >> (16 * (i & 1))) & 0xffffu;
        uint32 k = e & 0x1fffu;
        uint32 valid = (e & 0x4000u) ? 0u : ((srow[k >> 5] >> (k & 31u)) & 1u);
        if (i < 32) vb0 |= valid << i;
        else        vb1 |= valid << (i - 32);
    }
    int cnt = __popc(vb0) + __popc(vb1);
#pragma unroll
    for (int m = 1; m < 16; m <<= 1) cnt += __shfl_xor(cnt, m, 16);
    const float cv = fmaxf((float)cnt, 1.0f);
    const int ph = pcount[g];
    __syncthreads();  // all lanes done reading bitmask before row 0 overwrites it

    // ---- stage helper: 8 x global_load_lds(16B) per wave, linear dest ----
    auto STAGE = [&](int buf, int r) {
        const float* frow = feats + (size_t)(n * CC + c0 + r) * KK;
#pragma unroll
        for (int i = 0; i < 8; ++i) {
            const int seg = w * 8 + i;  // 32 segments of 256 floats
            __builtin_amdgcn_global_load_lds(
                (const __attribute__((address_space(1))) unsigned int*)(frow + seg * 256 + lane * 4),
                (__attribute__((address_space(3))) unsigned int*)&srow[buf * KK + seg * 256],
                16, 0, 0);
        }
    };

    STAGE(0, 0);
    for (int r = 0; r < CH; ++r) {
        const int cur = r & 1;
        const bool more = (r + 1 < CH);
        if (more) {
            STAGE(cur ^ 1, r + 1);  // next row in flight across the barrier
            asm volatile("s_waitcnt vmcnt(8)" ::: "memory");  // current row landed
        } else {
            asm volatile("s_waitcnt vmcnt(0)" ::: "memory");
        }
        __builtin_amdgcn_s_barrier();

        const uint32* rowp = &srow[cur * KK];
        float rs0 = 0.0f, rs1 = 0.0f;
        float rm0 = MAX_INIT, rm1 = MAX_INIT;
#pragma unroll
        for (int i = 0; i < 48; ++i) {
            uint32 k = (pk[i >> 1] >> (16 * (i & 1))) & 0x1fffu;
            float f = __uint_as_float(rowp[k]);
            uint32 vb = (i < 32) ? vb0 : vb1;
            uint32 sel = (vb >> (i & 31u)) & 1u;
            if (i & 1) { rm1 = fmaxf(rm1, f); rs1 += sel ? f : 0.0f; }
            else       { rm0 = fmaxf(rm0, f); rs0 += sel ? f : 0.0f; }
        }
        float rs = rs0 + rs1;
        float rm = fmaxf(rm0, rm1);
#pragma unroll
        for (int m = 1; m < 16; m <<= 1) {
            rs += __shfl_xor(rs, m, 16);
            rm = fmaxf(rm, __shfl_xor(rm, m, 16));
        }
        if (l == 0)
            out[(size_t)(n * CC + c0 + r) * PARTS + g] = rs / cv + (ph > 0 ? rm : 0.0f);

        if (more) __builtin_amdgcn_s_barrier();  // all waves done reading row[cur]
    }
}

extern "C" void kernel_launch(void* const* d_in, const int* in_sizes, int n_in,
                              void* d_out, int out_size, void* d_ws, size_t ws_size,
                              hipStream_t stream) {
    const float* feats  = (const float*)d_in[0];
    const int*   labels = (const int*)d_in[1];
    const int*   vm     = (const int*)d_in[2];
    float* out = (float*)d_out;

    int* pcount   = (int*)d_ws;
    u16* permbase = (u16*)((char*)d_ws + 64);

    sortA<<<1, TPB, 0, stream>>>(labels, pcount, permbase);
    pool_kernel<<<NN * NCH, TPB, 0, stream>>>(feats, permbase, pcount, vm, out);
}